// Round 1
// 89.977 us; speedup vs baseline: 1.0221x; 1.0221x over previous
//
#include <hip/hip_runtime.h>
#include <math.h>

static constexpr int BLK = 256;  // 4 waves
static constexpr int CH = 2048;  // scan-point chunk per block
static constexpr int SUB = 256;  // stage-tag granularity (3-bit stage id)
static constexpr int QB = 128;   // queries per block (32 per wave)

typedef _Float16 f16x8 __attribute__((ext_vector_type(8)));
typedef float f32x16 __attribute__((ext_vector_type(16)));

__device__ __forceinline__ unsigned f2u(float f) { return __float_as_uint(f); }
__device__ __forceinline__ float u2f(unsigned u) { return __uint_as_float(u); }
__device__ __forceinline__ unsigned pk(_Float16 a, _Float16 b) {
    union { _Float16 h[2]; unsigned u; } c; c.h[0] = a; c.h[1] = b; return c.u;
}

// B-frag from packed 8B point: (x,y,z,w) in k=0..3, zeros k=4..7 (finite, so
// 0*B contributes exactly 0 in the MFMA).
__device__ __forceinline__ f16x8 mk_b(uint2 v) {
    union { unsigned u[4]; f16x8 h; } c;
    c.u[0] = v.x; c.u[1] = v.y; c.u[2] = 0u; c.u[3] = 0u;
    return c.h;
}

// prep: sentinels + out=0 + pack both point sets to f16 (x,y,z,0.5|s|^2),
// 8 B/point. Packing once here replaces the per-block per-stage repack that
// main_kernel used to do 1024x per side.
__global__ void prep_kernel(const float* __restrict__ P,
                            const float* __restrict__ Ps,
                            unsigned long long* __restrict__ o2s,
                            unsigned* __restrict__ s2o,
                            uint2* __restrict__ pkP, uint2* __restrict__ pkPs,
                            float* __restrict__ out, int N, int M) {
    int i = blockIdx.x * blockDim.x + threadIdx.x;
    if (i < N) {
        o2s[i] = ~0ull;
        float x = P[3 * i], y = P[3 * i + 1], z = P[3 * i + 2];
        _Float16 hx = (_Float16)x, hy = (_Float16)y, hz = (_Float16)z;
        float fx = (float)hx, fy = (float)hy, fz = (float)hz;
        _Float16 hw = (_Float16)(0.5f * (fx * fx + fy * fy + fz * fz));
        pkP[i] = make_uint2(pk(hx, hy), pk(hz, hw));
    }
    if (i < M) {
        s2o[i] = 0xFFFFFFFFu;
        float x = Ps[3 * i], y = Ps[3 * i + 1], z = Ps[3 * i + 2];
        _Float16 hx = (_Float16)x, hy = (_Float16)y, hz = (_Float16)z;
        float fx = (float)hx, fy = (float)hy, fz = (float)hz;
        _Float16 hw = (_Float16)(0.5f * (fx * fx + fy * fy + fz * fz));
        pkPs[i] = make_uint2(pk(hx, hy), pk(hz, hw));
    }
    if (i == 0) out[0] = 0.0f;
}

// MFMA NN scan, barrier-free main loop.
// R20: previous depth-4 version was latency-bound at 42.6us — 16 barriers per
// block, each gating a global->pack->ds_write->ds_read chain at 4 waves/SIMD.
// Now: whole 16KB chunk staged once from the prepacked arrays (1 barrier),
// then 64 MFMAs run back-to-back from LDS (ds_read_b64, 2-way aliasing=free).
// Same depth-4 ILP, same stage-granular argmin tags + epilogue rescan.
__global__ void __launch_bounds__(BLK)
__attribute__((amdgpu_waves_per_eu(4, 4))) main_kernel(
    const float* __restrict__ P, const float* __restrict__ Ps,
    const uint2* __restrict__ pkP, const uint2* __restrict__ pkPs,
    unsigned long long* __restrict__ o2s, unsigned* __restrict__ s2o,
    int N, int M, int o2sBlocks, int o2sRG, int s2oRG) {
    __shared__ uint2 lds2[CH];  // 16 KB
    int tid = threadIdx.x;
    int lane = tid & 63, wave = tid >> 6;
    int n = lane & 31, half = lane >> 5;

    int bx = blockIdx.x;
    bool isO2S = bx < o2sBlocks;
    const float* qsrc; const float* ssrc;
    const uint2* pkq; const uint2* pks;
    int i0, j0;
    if (isO2S) {
        int rg = bx % o2sRG, c = bx / o2sRG;
        i0 = rg * QB + wave * 32; j0 = c * CH;
        qsrc = P; ssrc = Ps; pkq = pkP; pks = pkPs;  // queries=P, scan=Ps
    } else {
        int b = bx - o2sBlocks;
        int rg = b % s2oRG, c = b / s2oRG;
        i0 = rg * QB + wave * 32; j0 = c * CH;
        qsrc = Ps; ssrc = P; pkq = pkPs; pks = pkP;  // queries=Ps, scan=P
    }

    // stage the whole chunk once: 1024 uint4 = 4 per thread
    {
        const uint4* g4 = (const uint4*)pks + (j0 >> 1);
        uint4* l4 = (uint4*)lds2;
#pragma unroll
        for (int k = 0; k < 4; ++k) l4[k * BLK + tid] = g4[k * BLK + tid];
    }

    // A-frag from packed query: lane<32 holds (-x,-y,-z,1) at k=0..3; else 0.
    f16x8 af;
    {
        unsigned d0 = 0u, d1 = 0u;
        if (half == 0) {
            uint2 q = pkq[i0 + n];
            d0 = q.x ^ 0x80008000u;                          // (-x,-y)
            d1 = ((q.y ^ 0x00008000u) & 0x0000FFFFu) | 0x3C000000u;  // (-z,1.0h)
        }
        union { unsigned u[4]; f16x8 h; } a;
        a.u[0] = d0; a.u[1] = d1; a.u[2] = 0u; a.u[3] = 0u;
        af = a.h;
    }

    float runm[16];
#pragma unroll
    for (int r = 0; r < 16; ++r) runm[r] = __builtin_inff();
    f32x16 zacc = {};

    __syncthreads();

    for (int s = 0; s < CH / SUB; ++s) {
        float smin[16];
#pragma unroll
        for (int r = 0; r < 16; ++r) smin[r] = __builtin_inff();
#pragma unroll
        for (int t = 0; t < SUB / 32; t += 4) {
            int base = s * SUB + t * 32 + n;
            uint2 v0 = lds2[base];
            uint2 v1 = lds2[base + 32];
            uint2 v2 = lds2[base + 64];
            uint2 v3 = lds2[base + 96];
            f32x16 c0 = __builtin_amdgcn_mfma_f32_32x32x16_f16(af, mk_b(v0), zacc, 0, 0, 0);
            f32x16 c1 = __builtin_amdgcn_mfma_f32_32x32x16_f16(af, mk_b(v1), zacc, 0, 0, 0);
            f32x16 c2 = __builtin_amdgcn_mfma_f32_32x32x16_f16(af, mk_b(v2), zacc, 0, 0, 0);
            f32x16 c3 = __builtin_amdgcn_mfma_f32_32x32x16_f16(af, mk_b(v3), zacc, 0, 0, 0);
#pragma unroll
            for (int r = 0; r < 16; ++r) {
                smin[r] = fminf(fminf(smin[r], c0[r]), c1[r]);  // v_min3
                smin[r] = fminf(fminf(smin[r], c2[r]), c3[r]);  // v_min3
            }
        }
        // stage merge: tag with 3-bit stage id (o2s) or plain min (s2o)
        if (isO2S) {
#pragma unroll
            for (int r = 0; r < 16; ++r)
                runm[r] = fminf(runm[r], u2f((f2u(smin[r]) & ~0xFFu) | (unsigned)s));
        } else {
#pragma unroll
            for (int r = 0; r < 16; ++r)
                runm[r] = fminf(runm[r], smin[r]);
        }
    }

    if (isO2S) {  // repack low 8 bits: (stage<<5)|col so argmin survives lanes
#pragma unroll
        for (int r = 0; r < 16; ++r) {
            unsigned u = f2u(runm[r]);
            runm[r] = u2f((u & ~0xFFu) | ((u & 7u) << 5) | (unsigned)n);
        }
    }
    // butterfly min within each 32-lane half (masks 1..16 stay inside a half)
#pragma unroll
    for (int mask = 1; mask < 32; mask <<= 1) {
#pragma unroll
        for (int r = 0; r < 16; ++r)
            runm[r] = fminf(runm[r], __shfl_xor(runm[r], mask, 64));
    }
    if (n < 16) {  // one writer lane per reg per half
        int r = n;
        int row = (r & 3) + 8 * (r >> 2) + 4 * half;
        int i = i0 + row;
        float x = qsrc[3 * i], y = qsrc[3 * i + 1], z = qsrc[3 * i + 2];
        _Float16 hx = (_Float16)x, hy = (_Float16)y, hz = (_Float16)z;
        float fx = (float)hx, fy = (float)hy, fz = (float)hz;
        float nx = -fx, ny = -fy, nz = -fz;
        float pw = 0.5f * (fx * fx + fy * fy + fz * fz);
        if (isO2S) {
            // recover exact argmin: rescan the winning stage's 8 candidates
            unsigned uv = f2u(runm[r]);
            int sWin = (int)((uv >> 5) & 7u);
            int col = (int)(uv & 31u);
            float best = __builtin_inff();
            int bj = 0;
#pragma unroll
            for (int t = 0; t < 8; ++t) {
                int j = j0 + sWin * SUB + t * 32 + col;
                float sx = (float)(_Float16)ssrc[3 * j];
                float sy = (float)(_Float16)ssrc[3 * j + 1];
                float sz = (float)(_Float16)ssrc[3 * j + 2];
                float sw = 0.5f * (sx * sx + sy * sy + sz * sz);
                float m = fmaf(sx, nx, fmaf(sy, ny, fmaf(sz, nz, sw)));
                if (m < best) { best = m; bj = j; }
            }
            float d2 = fmaxf(2.0f * (pw + best), 0.0f);
            unsigned long long key =
                ((unsigned long long)f2u(d2) << 32) | (unsigned)bj;
            atomicMin(&o2s[i], key);
        } else {
            float d2 = fmaxf(2.0f * (pw + runm[r]), 0.0f);
            atomicMin(&s2o[i], f2u(d2));
        }
    }
}

// finish: one load per query, weight, block-reduce, one atomicAdd per block.
__global__ void finish_kernel(const unsigned* __restrict__ s2o,
                              const unsigned long long* __restrict__ o2s,
                              const float* __restrict__ prob,
                              float* __restrict__ out, int N, int M) {
    int t = blockIdx.x * BLK + threadIdx.x;
    float acc = 0.0f;
    if (t < M) {
        acc = sqrtf(u2f(s2o[t])) * prob[t];
    } else if (t < M + N) {
        unsigned long long key = o2s[t - M];
        float d2 = u2f((unsigned)(key >> 32));
        unsigned jj = (unsigned)(key & 0xFFFFFFFFu);
        acc = sqrtf(d2) * prob[jj];
    }
#pragma unroll
    for (int off = 32; off > 0; off >>= 1) acc += __shfl_down(acc, off, 64);
    __shared__ float wsum[BLK / 64];
    int lane = threadIdx.x & 63, wave = threadIdx.x >> 6;
    if (lane == 0) wsum[wave] = acc;
    __syncthreads();
    if (threadIdx.x == 0) {
        float s = 0.0f;
#pragma unroll
        for (int w = 0; w < BLK / 64; ++w) s += wsum[w];
        atomicAdd(out, s);
    }
}

extern "C" void kernel_launch(void* const* d_in, const int* in_sizes, int n_in,
                              void* d_out, int out_size, void* d_ws, size_t ws_size,
                              hipStream_t stream) {
    const float* P = (const float*)d_in[0];
    const float* Ps = (const float*)d_in[1];
    const float* prob = (const float*)d_in[2];
    int N = in_sizes[0] / 3;  // 32768
    int M = in_sizes[1] / 3;  // 8192
    float* out = (float*)d_out;

    char* ws = (char*)d_ws;
    unsigned long long* o2s = (unsigned long long*)ws;            // N*8 B
    unsigned* s2o = (unsigned*)(ws + (size_t)N * 8);              // M*4 B
    uint2* pkP = (uint2*)(ws + (size_t)N * 8 + (size_t)M * 4);    // N*8 B
    uint2* pkPs = (uint2*)(ws + (size_t)N * 16 + (size_t)M * 4);  // M*8 B

    int o2sRG = N / QB;                 // 256
    int s2oRG = M / QB;                 // 64
    int o2sBlocks = o2sRG * (M / CH);   // 256*4  = 1024
    int s2oBlocks = s2oRG * (N / CH);   // 64*16  = 1024
    int total = o2sBlocks + s2oBlocks;  // 2048

    prep_kernel<<<(N + BLK - 1) / BLK, BLK, 0, stream>>>(P, Ps, o2s, s2o,
                                                         pkP, pkPs, out, N, M);
    main_kernel<<<total, BLK, 0, stream>>>(P, Ps, pkP, pkPs, o2s, s2o, N, M,
                                           o2sBlocks, o2sRG, s2oRG);
    finish_kernel<<<(N + M + BLK - 1) / BLK, BLK, 0, stream>>>(s2o, o2s, prob,
                                                               out, N, M);
}

// Round 2
// 84.705 us; speedup vs baseline: 1.0857x; 1.0622x over previous
//
#include <hip/hip_runtime.h>
#include <math.h>

static constexpr int BLK = 256;  // 4 waves
static constexpr int CH = 4096;  // scan-point chunk per block (one round: 1024 blocks)
static constexpr int SUB = 512;  // stage-tag granularity (3-bit stage id, 8 stages)
static constexpr int QB = 128;   // queries per block (32 per wave)

typedef _Float16 f16x8 __attribute__((ext_vector_type(8)));
typedef float f32x16 __attribute__((ext_vector_type(16)));

__device__ __forceinline__ unsigned f2u(float f) { return __float_as_uint(f); }
__device__ __forceinline__ float u2f(unsigned u) { return __uint_as_float(u); }
__device__ __forceinline__ unsigned pk(_Float16 a, _Float16 b) {
    union { _Float16 h[2]; unsigned u; } c; c.h[0] = a; c.h[1] = b; return c.u;
}

// B-frag from packed 8B point: (x,y,z,w) in k=0..3, zeros k=4..7 (finite, so
// 0*B contributes exactly 0 in the MFMA).
__device__ __forceinline__ f16x8 mk_b(uint2 v) {
    union { unsigned u[4]; f16x8 h; } c;
    c.u[0] = v.x; c.u[1] = v.y; c.u[2] = 0u; c.u[3] = 0u;
    return c.h;
}

// prep: sentinels + out=0 + pack both point sets to f16 (x,y,z,0.5|s|^2).
__global__ void prep_kernel(const float* __restrict__ P,
                            const float* __restrict__ Ps,
                            unsigned long long* __restrict__ o2s,
                            unsigned* __restrict__ s2o,
                            uint2* __restrict__ pkP, uint2* __restrict__ pkPs,
                            float* __restrict__ out, int N, int M) {
    int i = blockIdx.x * blockDim.x + threadIdx.x;
    if (i < N) {
        o2s[i] = ~0ull;
        float x = P[3 * i], y = P[3 * i + 1], z = P[3 * i + 2];
        _Float16 hx = (_Float16)x, hy = (_Float16)y, hz = (_Float16)z;
        float fx = (float)hx, fy = (float)hy, fz = (float)hz;
        _Float16 hw = (_Float16)(0.5f * (fx * fx + fy * fy + fz * fz));
        pkP[i] = make_uint2(pk(hx, hy), pk(hz, hw));
    }
    if (i < M) {
        s2o[i] = 0xFFFFFFFFu;
        float x = Ps[3 * i], y = Ps[3 * i + 1], z = Ps[3 * i + 2];
        _Float16 hx = (_Float16)x, hy = (_Float16)y, hz = (_Float16)z;
        float fx = (float)hx, fy = (float)hy, fz = (float)hz;
        _Float16 hw = (_Float16)(0.5f * (fx * fx + fy * fy + fz * fz));
        pkPs[i] = make_uint2(pk(hx, hy), pk(hz, hw));
    }
    if (i == 0) out[0] = 0.0f;
}

// MFMA NN scan, barrier-free main loop, SINGLE occupancy round.
// R21: R20 (barrier-free, 2048 blocks) gave only -2us total; dispatch-id
// arithmetic says the timed window is ~45us harness reset traffic + 40us
// poison fill + ~10us of our kernels. This round: 1024 blocks (CH=4096,
// 32KB LDS, 4 blocks/CU exactly -> one round, no ramp tail), halved
// epilogues/atomics. SUB=512 keeps the 3-bit stage tag layout bit-identical;
// epilogue rescan covers 16 rows instead of 8 (writer lanes only).
__global__ void __launch_bounds__(BLK)
__attribute__((amdgpu_waves_per_eu(4, 4))) main_kernel(
    const float* __restrict__ P, const float* __restrict__ Ps,
    const uint2* __restrict__ pkP, const uint2* __restrict__ pkPs,
    unsigned long long* __restrict__ o2s, unsigned* __restrict__ s2o,
    int N, int M, int o2sBlocks, int o2sRG, int s2oRG) {
    __shared__ uint2 lds2[CH];  // 32 KB
    int tid = threadIdx.x;
    int lane = tid & 63, wave = tid >> 6;
    int n = lane & 31, half = lane >> 5;

    int bx = blockIdx.x;
    bool isO2S = bx < o2sBlocks;
    const float* qsrc; const float* ssrc;
    const uint2* pkq; const uint2* pks;
    int i0, j0;
    if (isO2S) {
        int rg = bx % o2sRG, c = bx / o2sRG;
        i0 = rg * QB + wave * 32; j0 = c * CH;
        qsrc = P; ssrc = Ps; pkq = pkP; pks = pkPs;  // queries=P, scan=Ps
    } else {
        int b = bx - o2sBlocks;
        int rg = b % s2oRG, c = b / s2oRG;
        i0 = rg * QB + wave * 32; j0 = c * CH;
        qsrc = Ps; ssrc = P; pkq = pkPs; pks = pkP;  // queries=Ps, scan=P
    }

    // stage the whole chunk once: 2048 uint4 = 8 per thread
    {
        const uint4* g4 = (const uint4*)pks + (j0 >> 1);
        uint4* l4 = (uint4*)lds2;
#pragma unroll
        for (int k = 0; k < 8; ++k) l4[k * BLK + tid] = g4[k * BLK + tid];
    }

    // A-frag from packed query: lane<32 holds (-x,-y,-z,1) at k=0..3; else 0.
    f16x8 af;
    {
        unsigned d0 = 0u, d1 = 0u;
        if (half == 0) {
            uint2 q = pkq[i0 + n];
            d0 = q.x ^ 0x80008000u;                          // (-x,-y)
            d1 = ((q.y ^ 0x00008000u) & 0x0000FFFFu) | 0x3C000000u;  // (-z,1.0h)
        }
        union { unsigned u[4]; f16x8 h; } a;
        a.u[0] = d0; a.u[1] = d1; a.u[2] = 0u; a.u[3] = 0u;
        af = a.h;
    }

    float runm[16];
#pragma unroll
    for (int r = 0; r < 16; ++r) runm[r] = __builtin_inff();
    f32x16 zacc = {};

    __syncthreads();

#pragma unroll 1  // keep code compact: 16 MFMAs + folds per stage iteration
    for (int s = 0; s < CH / SUB; ++s) {
        float smin[16];
#pragma unroll
        for (int r = 0; r < 16; ++r) smin[r] = __builtin_inff();
#pragma unroll
        for (int t = 0; t < SUB / 32; t += 4) {
            int base = s * SUB + t * 32 + n;
            uint2 v0 = lds2[base];
            uint2 v1 = lds2[base + 32];
            uint2 v2 = lds2[base + 64];
            uint2 v3 = lds2[base + 96];
            f32x16 c0 = __builtin_amdgcn_mfma_f32_32x32x16_f16(af, mk_b(v0), zacc, 0, 0, 0);
            f32x16 c1 = __builtin_amdgcn_mfma_f32_32x32x16_f16(af, mk_b(v1), zacc, 0, 0, 0);
            f32x16 c2 = __builtin_amdgcn_mfma_f32_32x32x16_f16(af, mk_b(v2), zacc, 0, 0, 0);
            f32x16 c3 = __builtin_amdgcn_mfma_f32_32x32x16_f16(af, mk_b(v3), zacc, 0, 0, 0);
#pragma unroll
            for (int r = 0; r < 16; ++r) {
                smin[r] = fminf(fminf(smin[r], c0[r]), c1[r]);  // v_min3
                smin[r] = fminf(fminf(smin[r], c2[r]), c3[r]);  // v_min3
            }
        }
        // stage merge: tag with 3-bit stage id (o2s) or plain min (s2o)
        if (isO2S) {
#pragma unroll
            for (int r = 0; r < 16; ++r)
                runm[r] = fminf(runm[r], u2f((f2u(smin[r]) & ~0xFFu) | (unsigned)s));
        } else {
#pragma unroll
            for (int r = 0; r < 16; ++r)
                runm[r] = fminf(runm[r], smin[r]);
        }
    }

    if (isO2S) {  // repack low 8 bits: (stage<<5)|col so argmin survives lanes
#pragma unroll
        for (int r = 0; r < 16; ++r) {
            unsigned u = f2u(runm[r]);
            runm[r] = u2f((u & ~0xFFu) | ((u & 7u) << 5) | (unsigned)n);
        }
    }
    // butterfly min within each 32-lane half (masks 1..16 stay inside a half)
#pragma unroll
    for (int mask = 1; mask < 32; mask <<= 1) {
#pragma unroll
        for (int r = 0; r < 16; ++r)
            runm[r] = fminf(runm[r], __shfl_xor(runm[r], mask, 64));
    }
    if (n < 16) {  // one writer lane per reg per half
        int r = n;
        int row = (r & 3) + 8 * (r >> 2) + 4 * half;
        int i = i0 + row;
        float x = qsrc[3 * i], y = qsrc[3 * i + 1], z = qsrc[3 * i + 2];
        _Float16 hx = (_Float16)x, hy = (_Float16)y, hz = (_Float16)z;
        float fx = (float)hx, fy = (float)hy, fz = (float)hz;
        float nx = -fx, ny = -fy, nz = -fz;
        float pw = 0.5f * (fx * fx + fy * fy + fz * fz);
        if (isO2S) {
            // recover exact argmin: rescan the winning stage's 16 candidates
            unsigned uv = f2u(runm[r]);
            int sWin = (int)((uv >> 5) & 7u);
            int col = (int)(uv & 31u);
            float best = __builtin_inff();
            int bj = 0;
#pragma unroll
            for (int t = 0; t < 16; ++t) {
                int j = j0 + sWin * SUB + t * 32 + col;
                float sx = (float)(_Float16)ssrc[3 * j];
                float sy = (float)(_Float16)ssrc[3 * j + 1];
                float sz = (float)(_Float16)ssrc[3 * j + 2];
                float sw = 0.5f * (sx * sx + sy * sy + sz * sz);
                float m = fmaf(sx, nx, fmaf(sy, ny, fmaf(sz, nz, sw)));
                if (m < best) { best = m; bj = j; }
            }
            float d2 = fmaxf(2.0f * (pw + best), 0.0f);
            unsigned long long key =
                ((unsigned long long)f2u(d2) << 32) | (unsigned)bj;
            atomicMin(&o2s[i], key);
        } else {
            float d2 = fmaxf(2.0f * (pw + runm[r]), 0.0f);
            atomicMin(&s2o[i], f2u(d2));
        }
    }
}

// finish: one load per query, weight, block-reduce, one atomicAdd per block.
__global__ void finish_kernel(const unsigned* __restrict__ s2o,
                              const unsigned long long* __restrict__ o2s,
                              const float* __restrict__ prob,
                              float* __restrict__ out, int N, int M) {
    int t = blockIdx.x * BLK + threadIdx.x;
    float acc = 0.0f;
    if (t < M) {
        acc = sqrtf(u2f(s2o[t])) * prob[t];
    } else if (t < M + N) {
        unsigned long long key = o2s[t - M];
        float d2 = u2f((unsigned)(key >> 32));
        unsigned jj = (unsigned)(key & 0xFFFFFFFFu);
        acc = sqrtf(d2) * prob[jj];
    }
#pragma unroll
    for (int off = 32; off > 0; off >>= 1) acc += __shfl_down(acc, off, 64);
    __shared__ float wsum[BLK / 64];
    int lane = threadIdx.x & 63, wave = threadIdx.x >> 6;
    if (lane == 0) wsum[wave] = acc;
    __syncthreads();
    if (threadIdx.x == 0) {
        float s = 0.0f;
#pragma unroll
        for (int w = 0; w < BLK / 64; ++w) s += wsum[w];
        atomicAdd(out, s);
    }
}

extern "C" void kernel_launch(void* const* d_in, const int* in_sizes, int n_in,
                              void* d_out, int out_size, void* d_ws, size_t ws_size,
                              hipStream_t stream) {
    const float* P = (const float*)d_in[0];
    const float* Ps = (const float*)d_in[1];
    const float* prob = (const float*)d_in[2];
    int N = in_sizes[0] / 3;  // 32768
    int M = in_sizes[1] / 3;  // 8192
    float* out = (float*)d_out;

    char* ws = (char*)d_ws;
    unsigned long long* o2s = (unsigned long long*)ws;            // N*8 B
    unsigned* s2o = (unsigned*)(ws + (size_t)N * 8);              // M*4 B
    uint2* pkP = (uint2*)(ws + (size_t)N * 8 + (size_t)M * 4);    // N*8 B
    uint2* pkPs = (uint2*)(ws + (size_t)N * 16 + (size_t)M * 4);  // M*8 B

    int o2sRG = N / QB;                 // 256
    int s2oRG = M / QB;                 // 64
    int o2sBlocks = o2sRG * (M / CH);   // 256*2 = 512
    int s2oBlocks = s2oRG * (N / CH);   // 64*8  = 512
    int total = o2sBlocks + s2oBlocks;  // 1024 = 4 blocks/CU, one round

    prep_kernel<<<(N + BLK - 1) / BLK, BLK, 0, stream>>>(P, Ps, o2s, s2o,
                                                         pkP, pkPs, out, N, M);
    main_kernel<<<total, BLK, 0, stream>>>(P, Ps, pkP, pkPs, o2s, s2o, N, M,
                                           o2sBlocks, o2sRG, s2oRG);
    finish_kernel<<<(N + M + BLK - 1) / BLK, BLK, 0, stream>>>(s2o, o2s, prob,
                                                               out, N, M);
}

// Round 4
// 83.611 us; speedup vs baseline: 1.0999x; 1.0131x over previous
//
#include <hip/hip_runtime.h>
#include <math.h>

static constexpr int BLK = 256;  // 4 waves
static constexpr int CH = 4096;  // scan-point chunk per block (one round: 1024 blocks)
static constexpr int SUB = 512;  // stage-tag granularity (3-bit stage id, 8 stages)
static constexpr int QB = 128;   // queries per block (32 per wave)

typedef _Float16 f16x8 __attribute__((ext_vector_type(8)));
typedef float f32x16 __attribute__((ext_vector_type(16)));

__device__ __forceinline__ unsigned f2u(float f) { return __float_as_uint(f); }
__device__ __forceinline__ float u2f(unsigned u) { return __uint_as_float(u); }
__device__ __forceinline__ unsigned pk(_Float16 a, _Float16 b) {
    union { _Float16 h[2]; unsigned u; } c; c.h[0] = a; c.h[1] = b; return c.u;
}

// B-frag from packed 8B point: (x,y,z,w) in k=0..3, zeros k=4..7 (finite, so
// 0*B contributes exactly 0 in the MFMA).
__device__ __forceinline__ f16x8 mk_b(uint2 v) {
    union { unsigned u[4]; f16x8 h; } c;
    c.u[0] = v.x; c.u[1] = v.y; c.u[2] = 0u; c.u[3] = 0u;
    return c.h;
}

// R23: 2-launch, no-prep structure. R22's cooperative fusion never launched
// (out==0 => launch error, likely graph-capture rejection). Same fusion gains
// by removing the cross-kernel dependencies instead:
//  - packing moved in-block (raw floats -> LDS; sources are L2-resident),
//  - atomicMin+sentinels replaced by plain stores to per-chunk partial slots
//    (o2s_part[2][N] u64, s2o_part[8][M] u32; no init needed),
//  - finish folds the partials (same lexicographic-min semantics).
// Scan geometry/tags/butterfly/rescan bit-identical to the passing R21 kernel.
__global__ void __launch_bounds__(BLK)
__attribute__((amdgpu_waves_per_eu(4, 4))) main_kernel(
    const float* __restrict__ P, const float* __restrict__ Ps,
    unsigned long long* __restrict__ o2s_part, unsigned* __restrict__ s2o_part,
    float* __restrict__ out,
    int N, int M, int o2sBlocks, int o2sRG, int s2oRG) {
    __shared__ uint2 lds2[CH];  // 32 KB
    int tid = threadIdx.x;
    int lane = tid & 63, wave = tid >> 6;
    int n = lane & 31, half = lane >> 5;
    int bx = blockIdx.x;

    if (bx == 0 && tid == 0) out[0] = 0.0f;  // belt & braces (harness memsets too)

    bool isO2S = bx < o2sBlocks;
    const float* qsrc; const float* ssrc;
    int i0, j0, c;
    if (isO2S) {
        int rg = bx % o2sRG; c = bx / o2sRG;
        i0 = rg * QB + wave * 32; j0 = c * CH;
        qsrc = P; ssrc = Ps;  // queries=P(N), scan=Ps(M)
    } else {
        int b = bx - o2sBlocks;
        int rg = b % s2oRG; c = b / s2oRG;
        i0 = rg * QB + wave * 32; j0 = c * CH;
        qsrc = Ps; ssrc = P;  // queries=Ps(M), scan=P(N)
    }

    // stage + pack own chunk from raw floats: 16 points per thread
    {
        const float* sp = ssrc + 3 * (size_t)j0;
#pragma unroll
        for (int k = 0; k < CH / BLK; ++k) {
            int p = k * BLK + tid;
            float x = sp[3 * p], y = sp[3 * p + 1], z = sp[3 * p + 2];
            _Float16 hx = (_Float16)x, hy = (_Float16)y, hz = (_Float16)z;
            float fx = (float)hx, fy = (float)hy, fz = (float)hz;
            _Float16 hw = (_Float16)(0.5f * (fx * fx + fy * fy + fz * fz));
            lds2[p] = make_uint2(pk(hx, hy), pk(hz, hw));
        }
    }

    // A-frag from raw query floats: lane<32 holds (-x,-y,-z,1) at k=0..3; else 0.
    f16x8 af;
    {
        float x = 0.f, y = 0.f, z = 0.f;
        if (half == 0) {
            int i = i0 + n;
            x = qsrc[3 * i]; y = qsrc[3 * i + 1]; z = qsrc[3 * i + 2];
        }
        _Float16 hx = (_Float16)x, hy = (_Float16)y, hz = (_Float16)z;
        _Float16 one = (half == 0) ? (_Float16)1.0f : (_Float16)0.0f;
        af = (f16x8){(_Float16)-hx, (_Float16)-hy, (_Float16)-hz, one,
                     (_Float16)0.0f, (_Float16)0.0f, (_Float16)0.0f, (_Float16)0.0f};
    }

    float runm[16];
#pragma unroll
    for (int r = 0; r < 16; ++r) runm[r] = __builtin_inff();
    f32x16 zacc = {};

    __syncthreads();

#pragma unroll 1  // keep code compact: 16 MFMAs + folds per stage iteration
    for (int s = 0; s < CH / SUB; ++s) {
        float smin[16];
#pragma unroll
        for (int r = 0; r < 16; ++r) smin[r] = __builtin_inff();
#pragma unroll
        for (int t = 0; t < SUB / 32; t += 4) {
            int base = s * SUB + t * 32 + n;
            uint2 v0 = lds2[base];
            uint2 v1 = lds2[base + 32];
            uint2 v2 = lds2[base + 64];
            uint2 v3 = lds2[base + 96];
            f32x16 c0 = __builtin_amdgcn_mfma_f32_32x32x16_f16(af, mk_b(v0), zacc, 0, 0, 0);
            f32x16 c1 = __builtin_amdgcn_mfma_f32_32x32x16_f16(af, mk_b(v1), zacc, 0, 0, 0);
            f32x16 c2 = __builtin_amdgcn_mfma_f32_32x32x16_f16(af, mk_b(v2), zacc, 0, 0, 0);
            f32x16 c3 = __builtin_amdgcn_mfma_f32_32x32x16_f16(af, mk_b(v3), zacc, 0, 0, 0);
#pragma unroll
            for (int r = 0; r < 16; ++r) {
                smin[r] = fminf(fminf(smin[r], c0[r]), c1[r]);  // v_min3
                smin[r] = fminf(fminf(smin[r], c2[r]), c3[r]);  // v_min3
            }
        }
        // stage merge: tag with 3-bit stage id (o2s) or plain min (s2o)
        if (isO2S) {
#pragma unroll
            for (int r = 0; r < 16; ++r)
                runm[r] = fminf(runm[r], u2f((f2u(smin[r]) & ~0xFFu) | (unsigned)s));
        } else {
#pragma unroll
            for (int r = 0; r < 16; ++r)
                runm[r] = fminf(runm[r], smin[r]);
        }
    }

    if (isO2S) {  // repack low 8 bits: (stage<<5)|col so argmin survives lanes
#pragma unroll
        for (int r = 0; r < 16; ++r) {
            unsigned u = f2u(runm[r]);
            runm[r] = u2f((u & ~0xFFu) | ((u & 7u) << 5) | (unsigned)n);
        }
    }
    // butterfly min within each 32-lane half (masks 1..16 stay inside a half)
#pragma unroll
    for (int mask = 1; mask < 32; mask <<= 1) {
#pragma unroll
        for (int r = 0; r < 16; ++r)
            runm[r] = fminf(runm[r], __shfl_xor(runm[r], mask, 64));
    }
    if (n < 16) {  // one writer lane per reg per half
        int r = n;
        int row = (r & 3) + 8 * (r >> 2) + 4 * half;
        int i = i0 + row;
        float x = qsrc[3 * i], y = qsrc[3 * i + 1], z = qsrc[3 * i + 2];
        _Float16 hx = (_Float16)x, hy = (_Float16)y, hz = (_Float16)z;
        float fx = (float)hx, fy = (float)hy, fz = (float)hz;
        float nx = -fx, ny = -fy, nz = -fz;
        float pw = 0.5f * (fx * fx + fy * fy + fz * fz);
        if (isO2S) {
            // recover exact argmin: rescan the winning stage's 16 candidates
            unsigned uv = f2u(runm[r]);
            int sWin = (int)((uv >> 5) & 7u);
            int col = (int)(uv & 31u);
            float best = __builtin_inff();
            int bj = 0;
#pragma unroll
            for (int t = 0; t < 16; ++t) {
                int j = j0 + sWin * SUB + t * 32 + col;
                float sx = (float)(_Float16)ssrc[3 * j];
                float sy = (float)(_Float16)ssrc[3 * j + 1];
                float sz = (float)(_Float16)ssrc[3 * j + 2];
                float sw = 0.5f * (sx * sx + sy * sy + sz * sz);
                float m = fmaf(sx, nx, fmaf(sy, ny, fmaf(sz, nz, sw)));
                if (m < best) { best = m; bj = j; }
            }
            float d2 = fmaxf(2.0f * (pw + best), 0.0f);
            unsigned long long key =
                ((unsigned long long)f2u(d2) << 32) | (unsigned)bj;
            o2s_part[(size_t)c * N + i] = key;  // plain store, no init needed
        } else {
            float d2 = fmaxf(2.0f * (pw + runm[r]), 0.0f);
            s2o_part[(size_t)c * M + i] = f2u(d2);
        }
    }
}

// finish: fold per-chunk partials, weight, block-reduce, one atomicAdd/block.
__global__ void finish_kernel(const unsigned* __restrict__ s2o_part,
                              const unsigned long long* __restrict__ o2s_part,
                              const float* __restrict__ prob,
                              float* __restrict__ out, int N, int M) {
    int t = blockIdx.x * BLK + threadIdx.x;
    float acc = 0.0f;
    if (t < M) {
        unsigned m = s2o_part[t];
#pragma unroll
        for (int cc = 1; cc < 8; ++cc) m = min(m, s2o_part[(size_t)cc * M + t]);
        acc = sqrtf(u2f(m)) * prob[t];
    } else if (t < M + N) {
        int i = t - M;
        unsigned long long k0 = o2s_part[i];
        unsigned long long k1 = o2s_part[(size_t)N + i];
        unsigned long long k = (k1 < k0) ? k1 : k0;
        float d2 = u2f((unsigned)(k >> 32));
        unsigned jj = (unsigned)(k & 0xFFFFFFFFu);
        acc = sqrtf(d2) * prob[jj];
    }
#pragma unroll
    for (int off = 32; off > 0; off >>= 1) acc += __shfl_down(acc, off, 64);
    __shared__ float wsum[BLK / 64];
    int lane = threadIdx.x & 63, wave = threadIdx.x >> 6;
    if (lane == 0) wsum[wave] = acc;
    __syncthreads();
    if (threadIdx.x == 0) {
        float s = 0.0f;
#pragma unroll
        for (int w = 0; w < BLK / 64; ++w) s += wsum[w];
        atomicAdd(out, s);
    }
}

extern "C" void kernel_launch(void* const* d_in, const int* in_sizes, int n_in,
                              void* d_out, int out_size, void* d_ws, size_t ws_size,
                              hipStream_t stream) {
    const float* P = (const float*)d_in[0];
    const float* Ps = (const float*)d_in[1];
    const float* prob = (const float*)d_in[2];
    int N = in_sizes[0] / 3;  // 32768
    int M = in_sizes[1] / 3;  // 8192
    float* out = (float*)d_out;

    char* ws = (char*)d_ws;
    unsigned long long* o2s_part = (unsigned long long*)ws;      // 2*N*8 = 512 KB
    unsigned* s2o_part = (unsigned*)(ws + (size_t)2 * N * 8);    // 8*M*4 = 256 KB

    int o2sRG = N / QB;                 // 256
    int s2oRG = M / QB;                 // 64
    int o2sBlocks = o2sRG * (M / CH);   // 256*2 = 512
    int s2oBlocks = s2oRG * (N / CH);   // 64*8  = 512
    int total = o2sBlocks + s2oBlocks;  // 1024 = 4 blocks/CU, one round

    main_kernel<<<total, BLK, 0, stream>>>(P, Ps, o2s_part, s2o_part, out, N, M,
                                           o2sBlocks, o2sRG, s2oRG);
    finish_kernel<<<(N + M + BLK - 1) / BLK, BLK, 0, stream>>>(s2o_part, o2s_part,
                                                               prob, out, N, M);
}